// Round 9
// baseline (323.768 us; speedup 1.0000x reference)
//
#include <hip/hip_runtime.h>

// GroupLinearBlock: out = einsum('nhd,hdf', (rmsnorm_h(x@W) + b)/sqrt2, K)
// R9: BK=32, 4 rotating LDS buffers (A 4x16KB + B 4x16KB = 128KB), depth-3
// prefetch with end-of-tile vmcnt(8) (2 tiles always in flight). A and B both
// staged as FLAT copies of precomputed LDS images ([kslot(4)][row/col(256)][16B],
// 2-way conflict-free reads). 2 phases/tile x 16 MFMA. Epilogue as R8.

typedef __attribute__((ext_vector_type(8))) __bf16 bf16x8;
typedef __attribute__((ext_vector_type(4))) float f32x4;
typedef __attribute__((ext_vector_type(8))) unsigned short ushort8;

__device__ __forceinline__ unsigned short bfbits(float f) {
  return __builtin_bit_cast(unsigned short, (__bf16)f);
}
__device__ __forceinline__ f32x4 mfma_bf16(bf16x8 a, bf16x8 b, f32x4 c) {
  return __builtin_amdgcn_mfma_f32_16x16x32_bf16(a, b, c, 0, 0, 0);
}
__device__ __forceinline__ void gl_lds16(const void* g, void* l) {
  __builtin_amdgcn_global_load_lds(
      (const __attribute__((address_space(1))) unsigned int*)g,
      (__attribute__((address_space(3))) unsigned int*)l, 16, 0, 0);
}

// ---- prep: x f32 -> A-images: ximg[rt(256)][t(32)] = 16KB block
//      [kslot(4)][row(256)][16B]; chunk(kslot,row) = bf16 x[rt*256+row][t*32+kslot*8..+8]
__global__ void cvt_x_img(const float* __restrict__ x, unsigned short* __restrict__ img) {
  const int rt = blockIdx.x, t = blockIdx.y, u = threadIdx.x;   // 256 thr
  const float* src = x + ((size_t)rt * 256 + u) * 1024 + t * 32;
  unsigned short* dst = img + ((size_t)rt * 32 + t) * 8192;     // 16KB block
  #pragma unroll
  for (int j = 0; j < 4; ++j) {
    f32x4 a = *reinterpret_cast<const f32x4*>(src + j * 8);
    f32x4 b = *reinterpret_cast<const f32x4*>(src + j * 8 + 4);
    ushort8 v;
    v[0] = bfbits(a[0]); v[1] = bfbits(a[1]); v[2] = bfbits(a[2]); v[3] = bfbits(a[3]);
    v[4] = bfbits(b[0]); v[5] = bfbits(b[1]); v[6] = bfbits(b[2]); v[7] = bfbits(b[3]);
    *reinterpret_cast<ushort8*>(dst + (size_t)(j * 256 + u) * 8) = v;
  }
}

// ---- prep: w_lin [k][n] f32 -> B-images: wb[ct(4)][t(32)][kc(4)][col(256)][8] bf16
__global__ void prep_w(const float* __restrict__ w, unsigned short* __restrict__ wb) {
  const int g = blockIdx.x * 256 + threadIdx.x;   // 0..131071 chunk id
  const int col = g & 255, kc = (g >> 8) & 3, t = (g >> 10) & 31, ct = g >> 15;
  const int k0 = t * 32 + kc * 8;
  ushort8 v;
  #pragma unroll
  for (int j = 0; j < 8; ++j) v[j] = bfbits(w[(size_t)(k0 + j) * 1024 + ct * 256 + col]);
  *reinterpret_cast<ushort8*>(wb + (size_t)g * 8) = v;
}

// ---- prep: kernel [16][d][f] f32 -> kt [16][f][d] bf16 ----
__global__ void transpose_k(const float* __restrict__ kin, unsigned short* __restrict__ kt) {
  __shared__ float tile[64][65];
  const int h = blockIdx.x;
  const int t = threadIdx.x;
  #pragma unroll
  for (int i = 0; i < 16; ++i) {
    int idx = i * 256 + t;
    tile[idx >> 6][idx & 63] = kin[(size_t)h * 4096 + idx];
  }
  __syncthreads();
  #pragma unroll
  for (int i = 0; i < 16; ++i) {
    int idx = i * 256 + t;
    kt[(size_t)h * 4096 + idx] = bfbits(tile[idx & 63][idx >> 6]);
  }
}

// ---- main: 1024 blocks x 512 threads; tile 256x256, K=1024, BK=32 ----
__global__ __launch_bounds__(512, 2)
void fused_main(const unsigned short* __restrict__ ximg,
                const float* __restrict__ nbias,
                const unsigned short* __restrict__ wb,
                const unsigned short* __restrict__ ktg_,
                float* __restrict__ out)
{
  // LDS 128KB: A bufs 0..64K (4 x 16KB), B bufs 64K..128K (4 x 16KB).
  // Buffer = [kslot(4)][row/col(256)][16B] (flat image copy; 2-way reads).
  // Epilogue reuses all 128KB as per-wave y (128x64 bf16, 16KB/wave).
  __shared__ __align__(16) unsigned char smem[131072];
  const int tid = threadIdx.x;
  const int wv = tid >> 6, lane = tid & 63, l15 = lane & 15, lg = lane >> 4;
  const int l7 = l15 & 7;
  const int wr = wv >> 2, wc = wv & 3;     // wave: rows wr*128, cols wc*64
  const int bid = blockIdx.x;
  const int v = (bid & 7) * 128 + (bid >> 3);   // XCD grouping (1024 % 8 == 0)
  const int rt = v >> 2, ct = v & 3;
  const size_t row0 = (size_t)rt * 256;

  const char* aimg = (const char*)ximg + (size_t)rt * 524288 + tid * 16;
  const char* bimg = (const char*)wb + (size_t)ct * 524288 + tid * 16;

  // fragment-read byte offsets within a 16KB buffer (2-way bank aliasing, free)
  const int aBase = lg * 4096 + (wr * 128 + l15) * 16;
  const int bBase = lg * 4096 + (wc * 64 + l15) * 16;

  f32x4 acc[8][4];
  const f32x4 z4 = {0.f, 0.f, 0.f, 0.f};
  #pragma unroll
  for (int mi = 0; mi < 8; ++mi)
    #pragma unroll
    for (int ni = 0; ni < 4; ++ni) acc[mi][ni] = z4;

  auto stageA = [&](int t, int bsel) {     // 16KB flat copy (2 instr)
    unsigned char* d = smem + (bsel << 14) + tid * 16;
    const char* s = aimg + (size_t)t * 16384;
    gl_lds16(s, d);
    gl_lds16(s + 8192, d + 8192);
  };
  auto stageB = [&](int t, int bsel) {
    unsigned char* d = smem + 65536 + (bsel << 14) + tid * 16;
    const char* s = bimg + (size_t)t * 16384;
    gl_lds16(s, d);
    gl_lds16(s + 8192, d + 8192);
  };

  // one K-tile: 2 phases x 16 MFMA; stages A/B of tile stageT interleaved
  auto tile_compute = [&](int csel, int ssel, bool doStage, int stageT) {
    const unsigned char* Ab = smem + (csel << 14);
    const unsigned char* Bb = smem + 65536 + (csel << 14);
    bf16x8 afr[4], bfr[4], ahr[4];
    // Ph0: reads (A m0-3 + B all) ; stage A(t+3) ; barrier ; MFMA ; barrier
    #pragma unroll
    for (int m = 0; m < 4; ++m)
      afr[m] = *reinterpret_cast<const bf16x8*>(Ab + aBase + m * 256);
    #pragma unroll
    for (int n = 0; n < 4; ++n)
      bfr[n] = *reinterpret_cast<const bf16x8*>(Bb + bBase + n * 256);
    if (doStage) stageA(stageT, ssel);
    __builtin_amdgcn_s_barrier();
    asm volatile("s_waitcnt lgkmcnt(0)" ::: "memory");
    __builtin_amdgcn_sched_barrier(0);
    __builtin_amdgcn_s_setprio(1);
    #pragma unroll
    for (int m = 0; m < 4; ++m)
      #pragma unroll
      for (int n = 0; n < 4; ++n)
        acc[m][n] = mfma_bf16(afr[m], bfr[n], acc[m][n]);
    __builtin_amdgcn_s_setprio(0);
    __builtin_amdgcn_s_barrier();
    // Ph1: reads (A m4-7) ; stage B(t+3) ; barrier ; MFMA
    #pragma unroll
    for (int m = 0; m < 4; ++m)
      ahr[m] = *reinterpret_cast<const bf16x8*>(Ab + aBase + (4 + m) * 256);
    if (doStage) stageB(stageT, ssel);
    __builtin_amdgcn_s_barrier();
    asm volatile("s_waitcnt lgkmcnt(0)" ::: "memory");
    __builtin_amdgcn_sched_barrier(0);
    __builtin_amdgcn_s_setprio(1);
    #pragma unroll
    for (int m = 0; m < 4; ++m)
      #pragma unroll
      for (int n = 0; n < 4; ++n)
        acc[4 + m][n] = mfma_bf16(ahr[m], bfr[n], acc[4 + m][n]);
    __builtin_amdgcn_s_setprio(0);
    // caller: end-of-tile vmcnt + barrier
  };

  // ---- prologue: stage tiles 0,1,2 (12 loads); wait tile0 (8 remain) ----
  stageA(0, 0); stageB(0, 0);
  stageA(1, 1); stageB(1, 1);
  stageA(2, 2); stageB(2, 2);
  asm volatile("s_waitcnt vmcnt(8)" ::: "memory");
  __builtin_amdgcn_s_barrier();

  // ---- main loop: t = 0..28, stage t+3, keep 2 tiles in flight ----
  for (int t = 0; t < 29; ++t) {
    tile_compute(t & 3, (t + 3) & 3, true, t + 3);
    asm volatile("s_waitcnt vmcnt(8)" ::: "memory");   // tile t+1 landed
    __builtin_amdgcn_s_barrier();
  }
  // ---- peel: t = 29, 30, 31 (no staging; drain) ----
  tile_compute(1, 0, false, 0);
  asm volatile("s_waitcnt vmcnt(4)" ::: "memory");     // tile 30 landed
  __builtin_amdgcn_s_barrier();
  tile_compute(2, 0, false, 0);
  asm volatile("s_waitcnt vmcnt(0)" ::: "memory");     // tile 31 landed
  __builtin_amdgcn_s_barrier();
  tile_compute(3, 0, false, 0);
  __syncthreads();   // full drain; repurpose LDS as per-wave y

  // ---- epilogue: per-head RMSNorm + bias blend -> y LDS -> GEMM2 ----
  const int h = ct * 4 + wc;
  unsigned short* yw = reinterpret_cast<unsigned short*>(smem + wv * 16384);  // 128x64
  const float* bb = nbias + (row0 + wr * 128) * 1024 + (size_t)h * 64 + l15;

  #pragma unroll
  for (int mi = 0; mi < 8; ++mi) {
    float ssq[4];
    #pragma unroll
    for (int r = 0; r < 4; ++r) {
      float p = 0.f;
      #pragma unroll
      for (int ni = 0; ni < 4; ++ni) { const float q = acc[mi][ni][r]; p += q * q; }
      ssq[r] = p;
    }
    #pragma unroll
    for (int s = 1; s < 16; s <<= 1)
      #pragma unroll
      for (int r = 0; r < 4; ++r) ssq[r] += __shfl_xor(ssq[r], s, 64);
    #pragma unroll
    for (int r = 0; r < 4; ++r) {
      const float rs = rsqrtf(ssq[r] * 0.015625f + 1e-6f);
      const int rl = mi * 16 + lg * 4 + r;            // row 0..127
      const float* bp = bb + (size_t)rl * 1024;
      #pragma unroll
      for (int ni = 0; ni < 4; ++ni) {
        const float y = (acc[mi][ni][r] * rs + bp[ni * 16]) * 0.70710678118654752f;
        const int sy = (ni * 2 + (l15 >> 3)) ^ (rl & 7);   // swizzled 16B slot
        yw[rl * 64 + sy * 8 + l7] = bfbits(y);
      }
    }
  }
  asm volatile("s_waitcnt lgkmcnt(0)" ::: "memory");   // y writes visible (own wave)

  // GEMM2: y[128][64] @ ktg_[h][f][d]
  const unsigned short* ktp = ktg_ + (size_t)h * 4096;
  bf16x8 b2[4][2];
  #pragma unroll
  for (int ff = 0; ff < 4; ++ff)
    #pragma unroll
    for (int ks = 0; ks < 2; ++ks)
      b2[ff][ks] = *reinterpret_cast<const bf16x8*>(ktp + (ff * 16 + l15) * 64 + ks * 32 + lg * 8);

  #pragma unroll
  for (int m2 = 0; m2 < 8; ++m2) {
    f32x4 a2[4] = {z4, z4, z4, z4};
    const int row = m2 * 16 + l15;
    #pragma unroll
    for (int ks = 0; ks < 2; ++ks) {
      const int sl = ((ks * 4 + lg) ^ l7);
      bf16x8 a = *reinterpret_cast<const bf16x8*>(yw + row * 64 + sl * 8);
      #pragma unroll
      for (int ff = 0; ff < 4; ++ff) a2[ff] = mfma_bf16(a, b2[ff][ks], a2[ff]);
    }
    float* ob = out + (row0 + wr * 128 + m2 * 16 + lg * 4) * 1024 + h * 64 + l15;
    #pragma unroll
    for (int ff = 0; ff < 4; ++ff)
      #pragma unroll
      for (int r = 0; r < 4; ++r)
        ob[(size_t)r * 1024 + ff * 16] = a2[ff][r];
  }
}

extern "C" void kernel_launch(void* const* d_in, const int* in_sizes, int n_in,
                              void* d_out, int out_size, void* d_ws, size_t ws_size,
                              hipStream_t stream) {
  const float* x  = (const float*)d_in[0];   // [65536][1024]
  const float* nb = (const float*)d_in[1];   // [65536][16][64]
  const float* wl = (const float*)d_in[2];   // [1024][1024]
  const float* kr = (const float*)d_in[3];   // [16][64][64]
  float* out = (float*)d_out;

  unsigned short* wbp = (unsigned short*)d_ws;                      // 2 MB W images
  unsigned short* ktp = wbp + 1048576;                              // 128 KB
  unsigned short* xip = (unsigned short*)((char*)d_ws + 2228224);   // 134 MB A images

  hipLaunchKernelGGL(prep_w, dim3(512), dim3(256), 0, stream, wl, wbp);
  hipLaunchKernelGGL(transpose_k, dim3(16), dim3(256), 0, stream, kr, ktp);
  hipLaunchKernelGGL(cvt_x_img, dim3(256, 32), dim3(256), 0, stream, x, xip);
  hipLaunchKernelGGL(fused_main, dim3(1024), dim3(512), 0, stream, xip, nb, wbp, ktp, out);
}